// Round 5
// baseline (674.860 us; speedup 1.0000x reference)
//
#include <hip/hip_runtime.h>
#include <stdint.h>

// BinarizeLinear inference: out = sign(X) @ sign(W) + bias
// XNOR-popcount GEMM, round 4: u32 words + bcnt-accumulate, b128 LDS reads
// with 16B-chunk XOR swizzle, global_load_lds staging (pre-swizzled source).

#define N_ROWS 8192
#define K_DIM  4096
#define O_DIM  4096
#define KW     64        // uint64 words per K-row (u32 view: 128 words, 512 B/row)

// ---------------- pack X: one wave per row, ballot packs 64 signs/step ------
__global__ __launch_bounds__(256) void pack_x_kernel(
        const float* __restrict__ X, uint64_t* __restrict__ Xb) {
    int wave = (int)((blockIdx.x * blockDim.x + threadIdx.x) >> 6);
    int lane = threadIdx.x & 63;
    if (wave >= N_ROWS) return;
    const float* xr = X + (size_t)wave * K_DIM;
    uint64_t* xbr = Xb + (size_t)wave * KW;
    #pragma unroll 4
    for (int w = 0; w < KW; ++w) {
        float v = xr[w * 64 + lane];
        unsigned long long m = __ballot(v > 0.0f);
        if (lane == 0) xbr[w] = (uint64_t)m;
    }
}

// ---------------- pack W: thread per output column, builds one word ---------
__global__ __launch_bounds__(256) void pack_w_kernel(
        const float* __restrict__ W, uint64_t* __restrict__ Wb) {
    int oc = blockIdx.x & 15;
    int w  = blockIdx.x >> 4;
    int o  = oc * 256 + threadIdx.x;
    const float* wp = W + (size_t)(w * 64) * O_DIM + o;
    uint64_t word = 0;
    #pragma unroll 8
    for (int p = 0; p < 64; ++p) {
        float v = wp[(size_t)p * O_DIM];     // coalesced across threads
        word |= (uint64_t)(v > 0.0f) << p;
    }
    Wb[(size_t)o * KW + w] = word;
}

// ---------------- XNOR GEMM --------------------------------------------------
// Tile 128x128, 256 threads, 8x8 outputs/thread. K processed in 4 chunks of
// 1024 bits (32 u32 = 8 x 16B "quads" per row). LDS: per operand 128 rows x
// 8 quads = 1024 uint4 (16 KiB), quads stored at slot (q ^ ((row>>3)&7))
// via pre-swizzled global source + linear global_load_lds dest (rule 21).
#define BM 128
#define BN 128
#define TM 8
#define TN 8

__global__ __launch_bounds__(256, 2) void xnor_gemm_kernel(
        const uint8_t* __restrict__ Xb, const uint8_t* __restrict__ Wb,
        const float* __restrict__ bias, float* __restrict__ out) {
    __shared__ uint4 lds4[2048];          // [0,1024): X panel, [1024,2048): W panel

    const int tid    = threadIdx.x;
    const int tile_m = blockIdx.x >> 5;   // 64 M-tiles
    const int tile_n = blockIdx.x & 31;   // 32 N-tiles
    const int brow   = tile_m * BM;
    const int bcol   = tile_n * BN;
    const int tx     = tid & 15;
    const int ty     = tid >> 4;
    const int widx   = tid >> 6;          // wave 0..3

    // byte offsets into lds4 for this thread's fragment rows (swizzle folded)
    int bxb[TM], bwb[TN];
    #pragma unroll
    for (int r = 0; r < TM; ++r)
        bxb[r] = ((ty * 8 + r) * 8 + (ty & 7)) << 4;
    #pragma unroll
    for (int c = 0; c < TN; ++c)
        bwb[c] = (1024 + (tx * 8 + c) * 8 + (tx & 7)) << 4;

    uint32_t acc[TM][TN] = {};

    const uint8_t* ldsb = (const uint8_t*)lds4;

    for (int kc = 0; kc < 4; ++kc) {
        __syncthreads();                  // prev-chunk readers done
        // stage: 4 iters x 256 threads x 16B per operand = 16 KiB each
        #pragma unroll
        for (int i = 0; i < 4; ++i) {
            int idx  = tid + 256 * i;
            int row  = idx >> 3;
            int srcc = (idx & 7) ^ ((idx >> 6) & 7);    // pre-swizzled source quad
            size_t goff = ((size_t)row << 9) + (kc << 7) + (srcc << 4);
            __builtin_amdgcn_global_load_lds(
                (const __attribute__((address_space(1))) void*)
                    (Xb + ((size_t)brow << 9) + goff),
                (__attribute__((address_space(3))) void*)
                    (lds4 + i * 256 + widx * 64),
                16, 0, 0);
            __builtin_amdgcn_global_load_lds(
                (const __attribute__((address_space(1))) void*)
                    (Wb + ((size_t)bcol << 9) + goff),
                (__attribute__((address_space(3))) void*)
                    (lds4 + 1024 + i * 256 + widx * 64),
                16, 0, 0);
        }
        asm volatile("s_waitcnt vmcnt(0)" ::: "memory");
        __syncthreads();

        #pragma unroll
        for (int kq = 0; kq < 8; ++kq) {
            uint4 xq[TM], wq[TN];
            #pragma unroll
            for (int r = 0; r < TM; ++r)
                xq[r] = *(const uint4*)(ldsb + (bxb[r] ^ (kq << 4)));
            #pragma unroll
            for (int c = 0; c < TN; ++c)
                wq[c] = *(const uint4*)(ldsb + (bwb[c] ^ (kq << 4)));
            #pragma unroll
            for (int r = 0; r < TM; ++r)
                #pragma unroll
                for (int c = 0; c < TN; ++c) {
                    uint32_t a = acc[r][c];
                    a += __builtin_popcount(xq[r].x ^ wq[c].x);
                    a += __builtin_popcount(xq[r].y ^ wq[c].y);
                    a += __builtin_popcount(xq[r].z ^ wq[c].z);
                    a += __builtin_popcount(xq[r].w ^ wq[c].w);
                    acc[r][c] = a;
                }
        }
    }

    // epilogue: dot = K_DIM - 2*popc_total; add bias; float4 stores
    float bv[TN];
    #pragma unroll
    for (int c = 0; c < TN; ++c) bv[c] = bias[bcol + tx * TN + c];

    #pragma unroll
    for (int r = 0; r < TM; ++r) {
        float vals[TN];
        #pragma unroll
        for (int c = 0; c < TN; ++c)
            vals[c] = (float)(K_DIM - 2 * (int)acc[r][c]) + bv[c];
        float4* op = (float4*)(out + (size_t)(brow + ty * TM + r) * O_DIM
                               + bcol + tx * TN);
        op[0] = make_float4(vals[0], vals[1], vals[2], vals[3]);
        op[1] = make_float4(vals[4], vals[5], vals[6], vals[7]);
    }
}

extern "C" void kernel_launch(void* const* d_in, const int* in_sizes, int n_in,
                              void* d_out, int out_size, void* d_ws, size_t ws_size,
                              hipStream_t stream) {
    const float* X    = (const float*)d_in[0];   // [8192, 4096]
    const float* W    = (const float*)d_in[1];   // [4096, 4096]
    const float* bias = (const float*)d_in[2];   // [4096]
    float* out        = (float*)d_out;           // [8192, 4096]

    uint64_t* Xb = (uint64_t*)d_ws;                                       // 4 MiB
    uint64_t* Wb = (uint64_t*)((uint8_t*)d_ws + (size_t)N_ROWS * KW * 8); // 2 MiB

    pack_x_kernel<<<N_ROWS / 4, 256, 0, stream>>>(X, Xb);
    pack_w_kernel<<<16 * 64, 256, 0, stream>>>(W, Wb);
    xnor_gemm_kernel<<<(N_ROWS / BM) * (O_DIM / BN), 256, 0, stream>>>(
        (const uint8_t*)Xb, (const uint8_t*)Wb, bias, out);
}

// Round 6
// 373.521 us; speedup vs baseline: 1.8068x; 1.8068x over previous
//
#include <hip/hip_runtime.h>
#include <stdint.h>

// BinarizeLinear inference: out = sign(X) @ sign(W) + bias
// XNOR-popcount GEMM, round 5: low-register-pressure inner loop (64 acc +
// 8 X-frags + 1 W-frag live), u32 bcnt-accumulate, swizzle folded into base
// indices, global_load_lds staging with pre-swizzled source (rule 21).

#define N_ROWS 8192
#define K_DIM  4096
#define O_DIM  4096
#define KW     64        // uint64 words per K-row (512 B/row packed)

// ---------------- pack X: one wave per row, ballot packs 64 signs/step ------
__global__ __launch_bounds__(256) void pack_x_kernel(
        const float* __restrict__ X, uint64_t* __restrict__ Xb) {
    int wave = (int)((blockIdx.x * blockDim.x + threadIdx.x) >> 6);
    int lane = threadIdx.x & 63;
    if (wave >= N_ROWS) return;
    const float* xr = X + (size_t)wave * K_DIM;
    uint64_t* xbr = Xb + (size_t)wave * KW;
    #pragma unroll 4
    for (int w = 0; w < KW; ++w) {
        float v = xr[w * 64 + lane];
        unsigned long long m = __ballot(v > 0.0f);
        if (lane == 0) xbr[w] = (uint64_t)m;
    }
}

// ---------------- pack W: thread per output column, builds one word ---------
__global__ __launch_bounds__(256) void pack_w_kernel(
        const float* __restrict__ W, uint64_t* __restrict__ Wb) {
    int oc = blockIdx.x & 15;
    int w  = blockIdx.x >> 4;
    int o  = oc * 256 + threadIdx.x;
    const float* wp = W + (size_t)(w * 64) * O_DIM + o;
    uint64_t word = 0;
    #pragma unroll 8
    for (int p = 0; p < 64; ++p) {
        float v = wp[(size_t)p * O_DIM];     // coalesced across threads
        word |= (uint64_t)(v > 0.0f) << p;
    }
    Wb[(size_t)o * KW + w] = word;
}

// ---------------- XNOR GEMM --------------------------------------------------
// Tile 128x128, 256 threads, 8x8 outputs/thread. K in 4 chunks of 1024 bits
// (8 x 16B "quads" per row). LDS per operand: 128 rows x 8 quads = 1024 uint4
// (16 KiB); slot s of row holds global quad s ^ ((row>>3)&7), achieved by
// pre-swizzling the global source while global_load_lds writes linearly.
#define BM 128
#define BN 128
#define TM 8
#define TN 8

__global__ __launch_bounds__(256) void xnor_gemm_kernel(
        const uint8_t* __restrict__ Xb, const uint8_t* __restrict__ Wb,
        const float* __restrict__ bias, float* __restrict__ out) {
    __shared__ uint4 lds4[2048];          // [0,1024): X panel, [1024,2048): W panel

    const int tid    = threadIdx.x;
    const int tile_m = blockIdx.x >> 5;   // 64 M-tiles
    const int tile_n = blockIdx.x & 31;   // 32 N-tiles
    const int brow   = tile_m * BM;
    const int bcol   = tile_n * BN;
    const int tx     = tid & 15;
    const int ty     = tid >> 4;
    const int widx   = tid >> 6;          // wave 0..3

    // uint4 base indices with swizzle low-bits folded in; row r/c adds 8*r
    // (bits >=3) and kq XORs bits <3, so (base ^ kq) + 8*r is exact.
    const int xbase0 = ty * 64 + (ty & 7);
    const int wbase0 = 1024 + tx * 64 + (tx & 7);

    uint32_t acc[TM][TN] = {};

    for (int kc = 0; kc < 4; ++kc) {
        __syncthreads();                  // prev-chunk readers done
        #pragma unroll
        for (int i = 0; i < 4; ++i) {
            int idx  = tid + 256 * i;
            int row  = idx >> 3;
            int srcc = (idx & 7) ^ ((idx >> 6) & 7);    // pre-swizzled source quad
            size_t goff = ((size_t)row << 9) + (kc << 7) + (srcc << 4);
            __builtin_amdgcn_global_load_lds(
                (const __attribute__((address_space(1))) void*)
                    (Xb + ((size_t)brow << 9) + goff),
                (__attribute__((address_space(3))) void*)
                    (lds4 + i * 256 + widx * 64),
                16, 0, 0);
            __builtin_amdgcn_global_load_lds(
                (const __attribute__((address_space(1))) void*)
                    (Wb + ((size_t)bcol << 9) + goff),
                (__attribute__((address_space(3))) void*)
                    (lds4 + 1024 + i * 256 + widx * 64),
                16, 0, 0);
        }
        asm volatile("s_waitcnt vmcnt(0)" ::: "memory");
        __syncthreads();

        for (int kq = 0; kq < 8; ++kq) {  // runtime loop: small code, acc not indexed by kq
            const uint4* xp = &lds4[xbase0 ^ kq];
            const uint4* wp = &lds4[wbase0 ^ kq];
            uint4 xq[TM];
            #pragma unroll
            for (int r = 0; r < TM; ++r) xq[r] = xp[8 * r];   // ds_read_b128, imm offset
            #pragma unroll
            for (int c = 0; c < TN; ++c) {
                uint4 wv = wp[8 * c];                          // one W frag live
                #pragma unroll
                for (int r = 0; r < TM; ++r) {
                    uint32_t a = acc[r][c];
                    a = __builtin_popcount(xq[r].x ^ wv.x) + a;   // v_bcnt accumulate
                    a = __builtin_popcount(xq[r].y ^ wv.y) + a;
                    a = __builtin_popcount(xq[r].z ^ wv.z) + a;
                    a = __builtin_popcount(xq[r].w ^ wv.w) + a;
                    acc[r][c] = a;
                }
            }
        }
    }

    // epilogue: dot = K_DIM - 2*popc_total; add bias; float4 stores
    float bv[TN];
    #pragma unroll
    for (int c = 0; c < TN; ++c) bv[c] = bias[bcol + tx * TN + c];

    #pragma unroll
    for (int r = 0; r < TM; ++r) {
        float vals[TN];
        #pragma unroll
        for (int c = 0; c < TN; ++c)
            vals[c] = (float)(K_DIM - 2 * (int)acc[r][c]) + bv[c];
        float4* op = (float4*)(out + (size_t)(brow + ty * TM + r) * O_DIM
                               + bcol + tx * TN);
        op[0] = make_float4(vals[0], vals[1], vals[2], vals[3]);
        op[1] = make_float4(vals[4], vals[5], vals[6], vals[7]);
    }
}

extern "C" void kernel_launch(void* const* d_in, const int* in_sizes, int n_in,
                              void* d_out, int out_size, void* d_ws, size_t ws_size,
                              hipStream_t stream) {
    const float* X    = (const float*)d_in[0];   // [8192, 4096]
    const float* W    = (const float*)d_in[1];   // [4096, 4096]
    const float* bias = (const float*)d_in[2];   // [4096]
    float* out        = (float*)d_out;           // [8192, 4096]

    uint64_t* Xb = (uint64_t*)d_ws;                                       // 4 MiB
    uint64_t* Wb = (uint64_t*)((uint8_t*)d_ws + (size_t)N_ROWS * KW * 8); // 2 MiB

    pack_x_kernel<<<N_ROWS / 4, 256, 0, stream>>>(X, Xb);
    pack_w_kernel<<<16 * 64, 256, 0, stream>>>(W, Wb);
    xnor_gemm_kernel<<<(N_ROWS / BM) * (O_DIM / BN), 256, 0, stream>>>(
        (const uint8_t*)Xb, (const uint8_t*)Wb, bias, out);
}

// Round 7
// 235.039 us; speedup vs baseline: 2.8713x; 1.5892x over previous
//
#include <hip/hip_runtime.h>
#include <stdint.h>

// BinarizeLinear inference: out = sign(X) @ sign(W) + bias
// Round 6: i8 MFMA path (mfma_i32_32x32x32_i8) — popcount path kept as
// ws_size fallback. X -> Xi8 (+-1), W -> bit-pack -> WT i8 [out][in] (+-1),
// then 128x128-tile double-buffered MFMA GEMM. Exact integer math.

#define N_ROWS 8192
#define K_DIM  4096
#define O_DIM  4096
#define KW     64

typedef int  int4v  __attribute__((ext_vector_type(4)));
typedef int  int16v __attribute__((ext_vector_type(16)));

// ====================== shared helpers (both paths) =========================
__global__ __launch_bounds__(256) void pack_w_kernel(
        const float* __restrict__ W, uint64_t* __restrict__ Wb) {
    int oc = blockIdx.x & 15;
    int w  = blockIdx.x >> 4;
    int o  = oc * 256 + threadIdx.x;
    const float* wp = W + (size_t)(w * 64) * O_DIM + o;
    uint64_t word = 0;
    #pragma unroll 8
    for (int p = 0; p < 64; ++p) {
        float v = wp[(size_t)p * O_DIM];     // coalesced across threads
        word |= (uint64_t)(v > 0.0f) << p;
    }
    Wb[(size_t)o * KW + w] = word;
}

// ====================== i8 MFMA path ========================================
// convert X -> i8 (+1/-1), 16 elems/thread
__global__ __launch_bounds__(256) void convert_x_kernel(
        const float* __restrict__ X, int8_t* __restrict__ Xi8) {
    size_t i = ((size_t)blockIdx.x * 256 + threadIdx.x) * 16;
    const float4* xp = (const float4*)(X + i);
    uint32_t ow[4];
    #pragma unroll
    for (int q = 0; q < 4; ++q) {
        float4 v = xp[q];
        uint32_t b0 = v.x > 0.0f ? 0x01u : 0xFFu;
        uint32_t b1 = v.y > 0.0f ? 0x01u : 0xFFu;
        uint32_t b2 = v.z > 0.0f ? 0x01u : 0xFFu;
        uint32_t b3 = v.w > 0.0f ? 0x01u : 0xFFu;
        ow[q] = b0 | (b1 << 8) | (b2 << 16) | (b3 << 24);
    }
    int4v o; o.x = ow[0]; o.y = ow[1]; o.z = ow[2]; o.w = ow[3];
    *(int4v*)(Xi8 + i) = o;
}

// expand bit-packed Wb[o][128 u32] -> WT[o][k] i8 (+1/-1); 1 u32 -> 32 B
__global__ __launch_bounds__(256) void expand_wt_kernel(
        const uint32_t* __restrict__ Wb32, int8_t* __restrict__ WT) {
    size_t t = (size_t)blockIdx.x * 256 + threadIdx.x;   // o*128 + j32
    uint32_t w = Wb32[t];
    uint32_t ow[8];
    #pragma unroll
    for (int q = 0; q < 8; ++q) {
        uint32_t v = 0;
        #pragma unroll
        for (int b = 0; b < 4; ++b)
            v |= (((w >> (4 * q + b)) & 1u) ? 0x01u : 0xFFu) << (8 * b);
        ow[q] = v;
    }
    int4v o0; o0.x = ow[0]; o0.y = ow[1]; o0.z = ow[2]; o0.w = ow[3];
    int4v o1; o1.x = ow[4]; o1.y = ow[5]; o1.z = ow[6]; o1.w = ow[7];
    int4v* dst = (int4v*)(WT + t * 32);
    dst[0] = o0; dst[1] = o1;
}

// GEMM: 128x128 tile, BK=128 i8 (128 B rows), 4 waves, each 64x64 out
// (2x2 frags of 32x32). T3-min double-buffered LDS; global_load_lds with
// pre-swizzled source (chunk ^= row&7), swizzled ds_read_b128 fragments.
__global__ __launch_bounds__(256) void i8_gemm_kernel(
        const int8_t* __restrict__ Xi8, const int8_t* __restrict__ WT,
        const float* __restrict__ bias, float* __restrict__ out) {
    __shared__ int8_t As[2][128 * 128];
    __shared__ int8_t Bs[2][128 * 128];

    const int tid  = threadIdx.x;
    const int bm   = blockIdx.x >> 5;      // 64 M-tiles
    const int bn   = blockIdx.x & 31;      // 32 N-tiles
    const int brow = bm * 128;
    const int bcol = bn * 128;
    const int lane = tid & 63;
    const int widx = tid >> 6;
    const int wrow = (widx >> 1) * 64;
    const int wcol = (widx & 1) * 64;
    const int l31  = lane & 31;
    const int lh   = lane >> 5;

    int16v acc[2][2];
    #pragma unroll
    for (int m = 0; m < 2; ++m)
        #pragma unroll
        for (int n = 0; n < 2; ++n)
            #pragma unroll
            for (int r = 0; r < 16; ++r) acc[m][n][r] = 0;

    // staging source offsets (per-thread constant part)
    // idx = tid + 256*i ; row = idx>>3 ; phys chunk p = idx&7 holds
    // global chunk p ^ (row&7)  (read applies the same XOR -> rule 21)
#define STAGE(buf, kc)                                                        \
    {                                                                         \
        _Pragma("unroll")                                                     \
        for (int i = 0; i < 4; ++i) {                                         \
            int idx = tid + 256 * i;                                          \
            int row = idx >> 3;                                               \
            int sc  = (idx & 7) ^ (row & 7);                                  \
            __builtin_amdgcn_global_load_lds(                                 \
                (const __attribute__((address_space(1))) void*)               \
                    (Xi8 + (size_t)(brow + row) * K_DIM + (kc) * 128 + sc * 16), \
                (__attribute__((address_space(3))) void*)                     \
                    (As[buf] + i * 4096 + widx * 1024), 16, 0, 0);            \
        }                                                                     \
        _Pragma("unroll")                                                     \
        for (int i = 0; i < 4; ++i) {                                         \
            int idx = tid + 256 * i;                                          \
            int row = idx >> 3;                                               \
            int sc  = (idx & 7) ^ (row & 7);                                  \
            __builtin_amdgcn_global_load_lds(                                 \
                (const __attribute__((address_space(1))) void*)               \
                    (WT + (size_t)(bcol + row) * K_DIM + (kc) * 128 + sc * 16), \
                (__attribute__((address_space(3))) void*)                     \
                    (Bs[buf] + i * 4096 + widx * 1024), 16, 0, 0);            \
        }                                                                     \
    }

    STAGE(0, 0);
    asm volatile("s_waitcnt vmcnt(0)" ::: "memory");
    __syncthreads();

    int cur = 0;
    for (int kc = 0; kc < K_DIM / 128; ++kc) {
        if (kc + 1 < K_DIM / 128) STAGE(cur ^ 1, kc + 1);

        #pragma unroll
        for (int ks = 0; ks < 4; ++ks) {
            int4v a[2], b[2];
            #pragma unroll
            for (int m = 0; m < 2; ++m) {
                int row   = wrow + m * 32 + l31;
                int chunk = (2 * ks + lh) ^ (row & 7);
                a[m] = *(const int4v*)(As[cur] + row * 128 + chunk * 16);
            }
            #pragma unroll
            for (int n = 0; n < 2; ++n) {
                int col   = wcol + n * 32 + l31;
                int chunk = (2 * ks + lh) ^ (col & 7);
                b[n] = *(const int4v*)(Bs[cur] + col * 128 + chunk * 16);
            }
            #pragma unroll
            for (int m = 0; m < 2; ++m)
                #pragma unroll
                for (int n = 0; n < 2; ++n)
                    acc[m][n] = __builtin_amdgcn_mfma_i32_32x32x32_i8(
                        a[m], b[n], acc[m][n], 0, 0, 0);
        }

        asm volatile("s_waitcnt vmcnt(0)" ::: "memory");
        __syncthreads();
        cur ^= 1;
    }

    // epilogue: C/D map col=lane&31, row=(reg&3)+8*(reg>>2)+4*(lane>>5)
    #pragma unroll
    for (int n = 0; n < 2; ++n) {
        float bv = bias[bcol + wcol + n * 32 + l31];
        #pragma unroll
        for (int m = 0; m < 2; ++m) {
            #pragma unroll
            for (int r = 0; r < 16; ++r) {
                int row = brow + wrow + m * 32 + (r & 3) + 8 * (r >> 2) + 4 * lh;
                int col = bcol + wcol + n * 32 + l31;
                out[(size_t)row * O_DIM + col] = (float)acc[m][n][r] + bv;
            }
        }
    }
#undef STAGE
}

// ====================== popcount fallback path (round-5, proven) ============
__global__ __launch_bounds__(256) void pack_x_kernel(
        const float* __restrict__ X, uint64_t* __restrict__ Xb) {
    int wave = (int)((blockIdx.x * blockDim.x + threadIdx.x) >> 6);
    int lane = threadIdx.x & 63;
    if (wave >= N_ROWS) return;
    const float* xr = X + (size_t)wave * K_DIM;
    uint64_t* xbr = Xb + (size_t)wave * KW;
    #pragma unroll 4
    for (int w = 0; w < KW; ++w) {
        float v = xr[w * 64 + lane];
        unsigned long long m = __ballot(v > 0.0f);
        if (lane == 0) xbr[w] = (uint64_t)m;
    }
}

__global__ __launch_bounds__(256) void xnor_gemm_kernel(
        const uint8_t* __restrict__ Xb, const uint8_t* __restrict__ Wb,
        const float* __restrict__ bias, float* __restrict__ out) {
    __shared__ uint4 lds4[2048];

    const int tid    = threadIdx.x;
    const int tile_m = blockIdx.x >> 5;
    const int tile_n = blockIdx.x & 31;
    const int brow   = tile_m * 128;
    const int bcol   = tile_n * 128;
    const int tx     = tid & 15;
    const int ty     = tid >> 4;
    const int widx   = tid >> 6;

    const int xbase0 = ty * 64 + (ty & 7);
    const int wbase0 = 1024 + tx * 64 + (tx & 7);

    uint32_t acc[8][8] = {};

    for (int kc = 0; kc < 4; ++kc) {
        __syncthreads();
        #pragma unroll
        for (int i = 0; i < 4; ++i) {
            int idx  = tid + 256 * i;
            int row  = idx >> 3;
            int srcc = (idx & 7) ^ ((idx >> 6) & 7);
            size_t goff = ((size_t)row << 9) + (kc << 7) + (srcc << 4);
            __builtin_amdgcn_global_load_lds(
                (const __attribute__((address_space(1))) void*)
                    (Xb + ((size_t)brow << 9) + goff),
                (__attribute__((address_space(3))) void*)
                    (lds4 + i * 256 + widx * 64), 16, 0, 0);
            __builtin_amdgcn_global_load_lds(
                (const __attribute__((address_space(1))) void*)
                    (Wb + ((size_t)bcol << 9) + goff),
                (__attribute__((address_space(3))) void*)
                    (lds4 + 1024 + i * 256 + widx * 64), 16, 0, 0);
        }
        asm volatile("s_waitcnt vmcnt(0)" ::: "memory");
        __syncthreads();

        for (int kq = 0; kq < 8; ++kq) {
            const uint4* xp = &lds4[xbase0 ^ kq];
            const uint4* wp = &lds4[wbase0 ^ kq];
            uint4 xq[8];
            #pragma unroll
            for (int r = 0; r < 8; ++r) xq[r] = xp[8 * r];
            #pragma unroll
            for (int c = 0; c < 8; ++c) {
                uint4 wv = wp[8 * c];
                #pragma unroll
                for (int r = 0; r < 8; ++r) {
                    uint32_t a = acc[r][c];
                    a = __builtin_popcount(xq[r].x ^ wv.x) + a;
                    a = __builtin_popcount(xq[r].y ^ wv.y) + a;
                    a = __builtin_popcount(xq[r].z ^ wv.z) + a;
                    a = __builtin_popcount(xq[r].w ^ wv.w) + a;
                    acc[r][c] = a;
                }
            }
        }
    }

    float bv[8];
    #pragma unroll
    for (int c = 0; c < 8; ++c) bv[c] = bias[bcol + tx * 8 + c];

    #pragma unroll
    for (int r = 0; r < 8; ++r) {
        float vals[8];
        #pragma unroll
        for (int c = 0; c < 8; ++c)
            vals[c] = (float)(K_DIM - 2 * (int)acc[r][c]) + bv[c];
        float4* op = (float4*)(out + (size_t)(brow + ty * 8 + r) * O_DIM
                               + bcol + tx * 8);
        op[0] = make_float4(vals[0], vals[1], vals[2], vals[3]);
        op[1] = make_float4(vals[4], vals[5], vals[6], vals[7]);
    }
}

// ====================== launcher ============================================
extern "C" void kernel_launch(void* const* d_in, const int* in_sizes, int n_in,
                              void* d_out, int out_size, void* d_ws, size_t ws_size,
                              hipStream_t stream) {
    const float* X    = (const float*)d_in[0];   // [8192, 4096]
    const float* W    = (const float*)d_in[1];   // [4096, 4096]
    const float* bias = (const float*)d_in[2];   // [4096]
    float* out        = (float*)d_out;           // [8192, 4096]

    const size_t XI8_BYTES = (size_t)N_ROWS * K_DIM;          // 32 MiB
    const size_t WT_BYTES  = (size_t)O_DIM * K_DIM;           // 16 MiB
    const size_t WB_BYTES  = (size_t)O_DIM * KW * 8;          //  2 MiB

    if (ws_size >= XI8_BYTES + WT_BYTES + WB_BYTES) {
        // ---------------- i8 MFMA path ----------------
        int8_t*   Xi8 = (int8_t*)d_ws;
        int8_t*   WT  = (int8_t*)d_ws + XI8_BYTES;
        uint64_t* Wb  = (uint64_t*)((uint8_t*)d_ws + XI8_BYTES + WT_BYTES);

        convert_x_kernel<<<(N_ROWS * K_DIM) / (256 * 16), 256, 0, stream>>>(X, Xi8);
        pack_w_kernel<<<16 * 64, 256, 0, stream>>>(W, Wb);
        expand_wt_kernel<<<(O_DIM * 128) / 256, 256, 0, stream>>>(
            (const uint32_t*)Wb, WT);
        i8_gemm_kernel<<<(N_ROWS / 128) * (O_DIM / 128), 256, 0, stream>>>(
            Xi8, WT, bias, out);
    } else {
        // ---------------- popcount fallback ----------------
        uint64_t* Xb = (uint64_t*)d_ws;
        uint64_t* Wb = (uint64_t*)((uint8_t*)d_ws + (size_t)N_ROWS * KW * 8);
        pack_x_kernel<<<N_ROWS / 4, 256, 0, stream>>>(X, Xb);
        pack_w_kernel<<<16 * 64, 256, 0, stream>>>(W, Wb);
        xnor_gemm_kernel<<<(N_ROWS / 128) * (O_DIM / 128), 256, 0, stream>>>(
            (const uint8_t*)Xb, (const uint8_t*)Wb, bias, out);
    }
}

// Round 8
// 193.165 us; speedup vs baseline: 3.4937x; 1.2168x over previous
//
#include <hip/hip_runtime.h>
#include <stdint.h>

// BinarizeLinear inference: out = sign(X) @ sign(W) + bias
// Round 8: i8 MFMA GEMM ported to the 256x256 8-phase schedule (T3+T4+T5):
// 512 thr / 8 waves, BK=128 i8 (byte-identical to bf16 template's BK=64),
// 128 KiB double-buffered LDS, per-phase {ds_read || gload-issue -> barrier ->
// setprio(1) 8x mfma_i32_32x32x32_i8}, vmcnt(0) aged ~3 phases at tile edge.

#define N_ROWS 8192
#define K_DIM  4096
#define O_DIM  4096
#define KW     64

typedef int int4v  __attribute__((ext_vector_type(4)));

// ====================== pack / convert helpers ==============================
__global__ __launch_bounds__(256) void pack_w_kernel(
        const float* __restrict__ W, uint64_t* __restrict__ Wb) {
    int oc = blockIdx.x & 15;
    int w  = blockIdx.x >> 4;
    int o  = oc * 256 + threadIdx.x;
    const float* wp = W + (size_t)(w * 64) * O_DIM + o;
    uint64_t word = 0;
    #pragma unroll 8
    for (int p = 0; p < 64; ++p) {
        float v = wp[(size_t)p * O_DIM];
        word |= (uint64_t)(v > 0.0f) << p;
    }
    Wb[(size_t)o * KW + w] = word;
}

__global__ __launch_bounds__(256) void convert_x_kernel(
        const float* __restrict__ X, int8_t* __restrict__ Xi8) {
    size_t i = ((size_t)blockIdx.x * 256 + threadIdx.x) * 16;
    const float4* xp = (const float4*)(X + i);
    uint32_t ow[4];
    #pragma unroll
    for (int q = 0; q < 4; ++q) {
        float4 v = xp[q];
        uint32_t b0 = v.x > 0.0f ? 0x01u : 0xFFu;
        uint32_t b1 = v.y > 0.0f ? 0x01u : 0xFFu;
        uint32_t b2 = v.z > 0.0f ? 0x01u : 0xFFu;
        uint32_t b3 = v.w > 0.0f ? 0x01u : 0xFFu;
        ow[q] = b0 | (b1 << 8) | (b2 << 16) | (b3 << 24);
    }
    int4v o; o.x = ow[0]; o.y = ow[1]; o.z = ow[2]; o.w = ow[3];
    *(int4v*)(Xi8 + i) = o;
}

__global__ __launch_bounds__(256) void expand_wt_kernel(
        const uint32_t* __restrict__ Wb32, int8_t* __restrict__ WT) {
    size_t t = (size_t)blockIdx.x * 256 + threadIdx.x;   // o*128 + j32
    uint32_t w = Wb32[t];
    uint32_t ow[8];
    #pragma unroll
    for (int q = 0; q < 8; ++q) {
        uint32_t v = 0;
        #pragma unroll
        for (int b = 0; b < 4; ++b)
            v |= (((w >> (4 * q + b)) & 1u) ? 0x01u : 0xFFu) << (8 * b);
        ow[q] = v;
    }
    int4v o0; o0.x = ow[0]; o0.y = ow[1]; o0.z = ow[2]; o0.w = ow[3];
    int4v o1; o1.x = ow[4]; o1.y = ow[5]; o1.z = ow[6]; o1.w = ow[7];
    int4v* dst = (int4v*)(WT + t * 32);
    dst[0] = o0; dst[1] = o1;
}

// ====================== 256x256 8-phase i8 GEMM =============================
// Grid 512 blocks (32 M x 16 N), 512 threads. Per-wave 128x64 out (4x2 of
// 32x32). LDS layout: [buf][A 32KB | B 32KB], buf in {0,1}. Row = 128 B;
// physical chunk p of row holds logical chunk p ^ (row&7) (rule-21 pair:
// pre-swizzled gload source + XOR on ds_read).
__global__ __launch_bounds__(512, 2) void i8_gemm256_kernel(
        const int8_t* __restrict__ Xi8, const int8_t* __restrict__ WT,
        const float* __restrict__ bias, float* __restrict__ out) {
    __shared__ int8_t lds[2 * 65536];    // 128 KiB

    const int tid  = threadIdx.x;
    // XCD-aware swizzle: 512 blocks, 512%8==0 -> bijective
    const int swzb = (blockIdx.x & 7) * 64 + (blockIdx.x >> 3);
    const int brow = (swzb >> 4) * 256;
    const int bcol = (swzb & 15) * 256;

    const int lane = tid & 63;
    const int wid  = tid >> 6;
    const int wrow = (wid >> 2) * 128;   // 2 M-groups
    const int wcol = (wid & 3) * 64;     // 4 N-groups
    const int l31  = lane & 31;
    const int lh16 = (lane >> 5) << 4;
    const int swz16 = (l31 & 7) << 4;

    const int arow_base = (wrow + l31) * 128;
    const int bcol_base = 32768 + (wcol + l31) * 128;

    // staging per-thread constants: idx = tid + 512*i, row = idx>>3 (+64*i)
    const int srow0 = tid >> 3;
    const int scq   = (((tid & 7) ^ ((tid >> 3) & 7)) << 4);
    const size_t ldst0 = (size_t)tid * 16;   // LDS byte offset of iter 0

    const int8_t* Asrc = Xi8 + (size_t)(brow + srow0) * K_DIM + scq;
    const int8_t* Bsrc = WT  + (size_t)(bcol + srow0) * K_DIM + scq;

#define GLOADS(srcbase, ldsoff, kt)                                           \
    {                                                                         \
        _Pragma("unroll")                                                     \
        for (int i = 0; i < 4; ++i) {                                         \
            __builtin_amdgcn_global_load_lds(                                 \
                (const __attribute__((address_space(1))) void*)               \
                    ((srcbase) + (size_t)(kt) * 128 + (size_t)i * 64 * K_DIM),\
                (__attribute__((address_space(3))) void*)                     \
                    (lds + (ldsoff) + ldst0 + i * 8192), 16, 0, 0);           \
        }                                                                     \
    }

    int4v acc00 = {0,0,0,0}, acc01 = {0,0,0,0}, acc10 = {0,0,0,0}, acc11 = {0,0,0,0};
    typedef int int16v __attribute__((ext_vector_type(16)));
    int16v c00 = 0, c01 = 0, c10 = 0, c11 = 0, c20 = 0, c21 = 0, c30 = 0, c31 = 0;

    // prologue: stage tile 0 into buf 0
    GLOADS(Asrc, 0, 0);
    GLOADS(Bsrc, 32768, 0);
    asm volatile("s_waitcnt vmcnt(0)" ::: "memory");
    __builtin_amdgcn_s_barrier();

#define PHASE(p, STAGE_BLK)                                                   \
    {                                                                         \
        const int xoff = (((p) << 5) + lh16) ^ swz16;                         \
        const int8_t* Ap = lds + curoff + arow_base + xoff;                   \
        const int8_t* Bp = lds + curoff + bcol_base + xoff;                   \
        int4v a0 = *(const int4v*)(Ap);                                       \
        int4v a1 = *(const int4v*)(Ap + 4096);                                \
        int4v a2 = *(const int4v*)(Ap + 8192);                                \
        int4v a3 = *(const int4v*)(Ap + 12288);                               \
        int4v b0 = *(const int4v*)(Bp);                                       \
        int4v b1 = *(const int4v*)(Bp + 4096);                                \
        STAGE_BLK;                                                            \
        __builtin_amdgcn_s_barrier();                                         \
        __builtin_amdgcn_s_setprio(1);                                        \
        c00 = __builtin_amdgcn_mfma_i32_32x32x32_i8(a0, b0, c00, 0, 0, 0);    \
        c01 = __builtin_amdgcn_mfma_i32_32x32x32_i8(a0, b1, c01, 0, 0, 0);    \
        c10 = __builtin_amdgcn_mfma_i32_32x32x32_i8(a1, b0, c10, 0, 0, 0);    \
        c11 = __builtin_amdgcn_mfma_i32_32x32x32_i8(a1, b1, c11, 0, 0, 0);    \
        c20 = __builtin_amdgcn_mfma_i32_32x32x32_i8(a2, b0, c20, 0, 0, 0);    \
        c21 = __builtin_amdgcn_mfma_i32_32x32x32_i8(a2, b1, c21, 0, 0, 0);    \
        c30 = __builtin_amdgcn_mfma_i32_32x32x32_i8(a3, b0, c30, 0, 0, 0);    \
        c31 = __builtin_amdgcn_mfma_i32_32x32x32_i8(a3, b1, c31, 0, 0, 0);    \
        __builtin_amdgcn_s_setprio(0);                                        \
    }

    for (int t = 0; t < K_DIM / 128; ++t) {
        const int curoff = (t & 1) << 16;
        const int nxtoff = curoff ^ 65536;
        const bool pf = (t < K_DIM / 128 - 1);

        PHASE(0, { if (pf) GLOADS(Asrc, nxtoff, t + 1); });
        __builtin_amdgcn_s_barrier();
        PHASE(1, { if (pf) GLOADS(Bsrc, nxtoff + 32768, t + 1); });
        __builtin_amdgcn_s_barrier();
        PHASE(2, {});
        __builtin_amdgcn_s_barrier();
        PHASE(3, {});
        asm volatile("s_waitcnt vmcnt(0)" ::: "memory");
        __builtin_amdgcn_s_barrier();
    }
#undef PHASE
#undef GLOADS

    // epilogue: C/D map col=lane&31, row=(r&3)+8*(r>>2)+4*(lane>>5)
    const int lh = lane >> 5;
    float bv0 = bias[bcol + wcol + l31];
    float bv1 = bias[bcol + wcol + 32 + l31];
    const size_t obase = (size_t)(brow + wrow) * O_DIM + bcol + wcol;

#define CWRITE(cm, m, n, bv)                                                  \
    {                                                                         \
        _Pragma("unroll")                                                     \
        for (int r = 0; r < 16; ++r) {                                        \
            int rl = (r & 3) + 8 * (r >> 2) + 4 * lh;                         \
            out[obase + (size_t)((m) * 32 + rl) * O_DIM + (n) * 32 + l31] =   \
                (float)cm[r] + (bv);                                          \
        }                                                                     \
    }

    CWRITE(c00, 0, 0, bv0); CWRITE(c01, 0, 1, bv1);
    CWRITE(c10, 1, 0, bv0); CWRITE(c11, 1, 1, bv1);
    CWRITE(c20, 2, 0, bv0); CWRITE(c21, 2, 1, bv1);
    CWRITE(c30, 3, 0, bv0); CWRITE(c31, 3, 1, bv1);
#undef CWRITE
    (void)acc00; (void)acc01; (void)acc10; (void)acc11;
}

// ====================== popcount fallback (round-5, proven) =================
__global__ __launch_bounds__(256) void pack_x_kernel(
        const float* __restrict__ X, uint64_t* __restrict__ Xb) {
    int wave = (int)((blockIdx.x * blockDim.x + threadIdx.x) >> 6);
    int lane = threadIdx.x & 63;
    if (wave >= N_ROWS) return;
    const float* xr = X + (size_t)wave * K_DIM;
    uint64_t* xbr = Xb + (size_t)wave * KW;
    #pragma unroll 4
    for (int w = 0; w < KW; ++w) {
        float v = xr[w * 64 + lane];
        unsigned long long m = __ballot(v > 0.0f);
        if (lane == 0) xbr[w] = (uint64_t)m;
    }
}

__global__ __launch_bounds__(256) void xnor_gemm_kernel(
        const uint8_t* __restrict__ Xb, const uint8_t* __restrict__ Wb,
        const float* __restrict__ bias, float* __restrict__ out) {
    __shared__ uint4 lds4[2048];
    const int tid    = threadIdx.x;
    const int brow   = (blockIdx.x >> 5) * 128;
    const int bcol   = (blockIdx.x & 31) * 128;
    const int tx     = tid & 15;
    const int ty     = tid >> 4;
    const int widx   = tid >> 6;
    const int xbase0 = ty * 64 + (ty & 7);
    const int wbase0 = 1024 + tx * 64 + (tx & 7);
    uint32_t acc[8][8] = {};
    for (int kc = 0; kc < 4; ++kc) {
        __syncthreads();
        #pragma unroll
        for (int i = 0; i < 4; ++i) {
            int idx  = tid + 256 * i;
            int row  = idx >> 3;
            int srcc = (idx & 7) ^ ((idx >> 6) & 7);
            size_t goff = ((size_t)row << 9) + (kc << 7) + (srcc << 4);
            __builtin_amdgcn_global_load_lds(
                (const __attribute__((address_space(1))) void*)
                    (Xb + ((size_t)brow << 9) + goff),
                (__attribute__((address_space(3))) void*)
                    (lds4 + i * 256 + widx * 64), 16, 0, 0);
            __builtin_amdgcn_global_load_lds(
                (const __attribute__((address_space(1))) void*)
                    (Wb + ((size_t)bcol << 9) + goff),
                (__attribute__((address_space(3))) void*)
                    (lds4 + 1024 + i * 256 + widx * 64), 16, 0, 0);
        }
        asm volatile("s_waitcnt vmcnt(0)" ::: "memory");
        __syncthreads();
        for (int kq = 0; kq < 8; ++kq) {
            const uint4* xp = &lds4[xbase0 ^ kq];
            const uint4* wp = &lds4[wbase0 ^ kq];
            uint4 xq[8];
            #pragma unroll
            for (int r = 0; r < 8; ++r) xq[r] = xp[8 * r];
            #pragma unroll
            for (int c = 0; c < 8; ++c) {
                uint4 wv = wp[8 * c];
                #pragma unroll
                for (int r = 0; r < 8; ++r) {
                    uint32_t a = acc[r][c];
                    a = __builtin_popcount(xq[r].x ^ wv.x) + a;
                    a = __builtin_popcount(xq[r].y ^ wv.y) + a;
                    a = __builtin_popcount(xq[r].z ^ wv.z) + a;
                    a = __builtin_popcount(xq[r].w ^ wv.w) + a;
                    acc[r][c] = a;
                }
            }
        }
    }
    float bv[8];
    #pragma unroll
    for (int c = 0; c < 8; ++c) bv[c] = bias[bcol + tx * 8 + c];
    #pragma unroll
    for (int r = 0; r < 8; ++r) {
        float vals[8];
        #pragma unroll
        for (int c = 0; c < 8; ++c)
            vals[c] = (float)(K_DIM - 2 * (int)acc[r][c]) + bv[c];
        float4* op = (float4*)(out + (size_t)(brow + ty * 8 + r) * O_DIM
                               + bcol + tx * 8);
        op[0] = make_float4(vals[0], vals[1], vals[2], vals[3]);
        op[1] = make_float4(vals[4], vals[5], vals[6], vals[7]);
    }
}

// ====================== launcher ============================================
extern "C" void kernel_launch(void* const* d_in, const int* in_sizes, int n_in,
                              void* d_out, int out_size, void* d_ws, size_t ws_size,
                              hipStream_t stream) {
    const float* X    = (const float*)d_in[0];
    const float* W    = (const float*)d_in[1];
    const float* bias = (const float*)d_in[2];
    float* out        = (float*)d_out;

    const size_t XI8_BYTES = (size_t)N_ROWS * K_DIM;
    const size_t WT_BYTES  = (size_t)O_DIM * K_DIM;
    const size_t WB_BYTES  = (size_t)O_DIM * KW * 8;

    if (ws_size >= XI8_BYTES + WT_BYTES + WB_BYTES) {
        int8_t*   Xi8 = (int8_t*)d_ws;
        int8_t*   WT  = (int8_t*)d_ws + XI8_BYTES;
        uint64_t* Wb  = (uint64_t*)((uint8_t*)d_ws + XI8_BYTES + WT_BYTES);

        convert_x_kernel<<<(N_ROWS * K_DIM) / (256 * 16), 256, 0, stream>>>(X, Xi8);
        pack_w_kernel<<<16 * 64, 256, 0, stream>>>(W, Wb);
        expand_wt_kernel<<<(O_DIM * 128) / 256, 256, 0, stream>>>(
            (const uint32_t*)Wb, WT);
        i8_gemm256_kernel<<<(N_ROWS / 256) * (O_DIM / 256), 512, 0, stream>>>(
            Xi8, WT, bias, out);
    } else {
        uint64_t* Xb = (uint64_t*)d_ws;
        uint64_t* Wb = (uint64_t*)((uint8_t*)d_ws + (size_t)N_ROWS * KW * 8);
        pack_x_kernel<<<N_ROWS / 4, 256, 0, stream>>>(X, Xb);
        pack_w_kernel<<<16 * 64, 256, 0, stream>>>(W, Wb);
        xnor_gemm_kernel<<<(N_ROWS / 128) * (O_DIM / 128), 256, 0, stream>>>(
            (const uint8_t*)Xb, (const uint8_t*)Wb, bias, out);
    }
}